// Round 1
// baseline (177.648 us; speedup 1.0000x reference)
//
#include <hip/hip_runtime.h>
#include <stdint.h>

// ---------------------------------------------------------------------------
// MaskedAttentionHead: B=4, S=2048, d_model=1024, d_k=64
// R9: proj was latency-bound (MfmaUtil 2.7 / VALUBusy 7.9 / occ 17% — all
// idle at 40.2 us vs ~17 us HBM floor). Cause: 34 KB wq LDS staging of an
// L2-resident 128 KB W panel cost half the LDS (-> 2 blocks/CU) and 7
// serializing barriers per block. Fix: W B-frags read DIRECTLY from global
// in MFMA lane pattern (16x64B segments, L2-hot); wq + all mid-loop barriers
// deleted; LDS 67->33 KB -> 4 blocks/CU, bounds(256,4), 16 waves/CU.
// X pure-streaming burst (R8 win) and combine epilogue unchanged.
// attn/wcvt unchanged from R7 (attn still unprofiled).
// ---------------------------------------------------------------------------

typedef __bf16 bf16x8 __attribute__((ext_vector_type(8)));
typedef float  f32x4  __attribute__((ext_vector_type(4)));
typedef unsigned short u16;
typedef unsigned int   u32;

__device__ __forceinline__ u16 f2bf(float f) {
  u32 u = __float_as_uint(f);
  u += 0x7fffu + ((u >> 16) & 1u);          // round-to-nearest-even
  return (u16)(u >> 16);
}

// --------------------------- W fp32 -> bf16 --------------------------------
__global__ __launch_bounds__(256) void wcvt_kernel(
    const float* __restrict__ Wq, const float* __restrict__ Wk,
    const float* __restrict__ Wv, u16* __restrict__ Wbf) {
  int i = (blockIdx.x * 256 + threadIdx.x) * 4;   // 3*64*1024 = 196608 total
  const float* src = (i < 65536) ? Wq : (i < 131072) ? Wk : Wv;
  int off = i & 65535;
  float4 f = *(const float4*)(src + off);
  *(ushort4*)(Wbf + i) = make_ushort4(f2bf(f.x), f2bf(f.y), f2bf(f.z), f2bf(f.w));
}

// --------------------------- projections -----------------------------------
// grid 1536 (which = bx%3, 512 row-blocks), block 256 (4 waves), 4 blocks/CU.
// Block owns 16 rows. Wave w stages rows w*4..w*4+3 (16 contiguous float4
// loads -> 64 named VGPRs -> cvt -> LDS). Compute: wave's 64-wide k-slice per
// quarter qq; A-frag from padded LDS (2-way = free), W B-frag straight from
// global (L2-resident; 16 rows x 64B per load). No barriers in the K-loop.
// Combine 4 k-partials via os overlay on xl.
__global__ __launch_bounds__(256, 4) void proj_kernel(
    const float* __restrict__ q, const float* __restrict__ k,
    const float* __restrict__ v, const u16* __restrict__ Wbf,
    u16* __restrict__ qh, u16* __restrict__ kh, u16* __restrict__ vhT) {
  __shared__ u16 xl[16][1032];   // X tile bf16; stride 2064 B -> 2-way (free)
  const int tid = threadIdx.x;
  const int lane = tid & 63, w = tid >> 6;
  const int c16 = lane & 15, quad = lane >> 4;
  const int which = blockIdx.x % 3;
  const int r0 = (blockIdx.x / 3) * 16;
  const float* X = (which == 0) ? q : (which == 1) ? k : v;
  const u16* wsrc = Wbf + which * 65536;

  // ---- X burst: 16 contiguous 1-KB float4 loads (wave's 4 rows) ----
  const float* xgw = X + (size_t)(r0 + w * 4) * 1024 + lane * 4;
  float4 ar[16];
#pragma unroll
  for (int i = 0; i < 16; i++) ar[i] = *(const float4*)(xgw + i * 256);

  // ---- X cvt -> LDS ----
#pragma unroll
  for (int i = 0; i < 16; i++) {
    ushort4 pk = make_ushort4(f2bf(ar[i].x), f2bf(ar[i].y),
                              f2bf(ar[i].z), f2bf(ar[i].w));
    *(ushort4*)&xl[w * 4 + (i >> 2)][(i & 3) * 256 + lane * 4] = pk;
  }
  __syncthreads();

  f32x4 acc[4];
#pragma unroll
  for (int nt = 0; nt < 4; nt++)
#pragma unroll
    for (int j = 0; j < 4; j++) acc[nt][j] = 0.0f;

  // W row base for this lane's B-frags: row = nt*16 + c16, col = qq*256 + kin
  const u16* wr = wsrc + (size_t)c16 * 1024;

#pragma unroll
  for (int qq = 0; qq < 4; qq++) {
#pragma unroll
    for (int ks = 0; ks < 2; ks++) {
      const int kin = w * 64 + ks * 32 + quad * 8;       // col within quarter
      bf16x8 af = *(const bf16x8*)&xl[c16][qq * 256 + kin];
#pragma unroll
      for (int nt = 0; nt < 4; nt++) {
        bf16x8 wf = *(const bf16x8*)(wr + (size_t)nt * 16384 + qq * 256 + kin);
        acc[nt] = __builtin_amdgcn_mfma_f32_16x16x32_bf16(af, wf, acc[nt], 0, 0, 0);
      }
    }
  }

  // ---- combine 4 k-partials via os overlay on xl (xl dead) ----
  __syncthreads();
  float* osp = (float*)&xl[0][0];            // os[w][16][64] = 16 KB
#pragma unroll
  for (int nt = 0; nt < 4; nt++)
#pragma unroll
    for (int rr = 0; rr < 4; rr++)
      osp[((size_t)w * 16 + quad * 4 + rr) * 64 + nt * 16 + c16] = acc[nt][rr];
  __syncthreads();

  if (which == 2) {
    const int col = tid >> 2, s4 = (tid & 3) * 4;
    float s[4];
#pragma unroll
    for (int rr = 0; rr < 4; rr++)
      s[rr] = osp[(0 * 16 + s4 + rr) * 64 + col] + osp[(1 * 16 + s4 + rr) * 64 + col] +
              osp[(2 * 16 + s4 + rr) * 64 + col] + osp[(3 * 16 + s4 + rr) * 64 + col];
    const int bb = r0 >> 11, s0 = (r0 & 2047) + s4;
    ushort4 pk = make_ushort4(f2bf(s[0]), f2bf(s[1]), f2bf(s[2]), f2bf(s[3]));
    *(ushort4*)(vhT + ((size_t)bb * 64 + col) * 2048 + s0) = pk;
  } else {
    u16* out = (which == 0) ? qh : kh;
    const int row = tid >> 4, c4 = (tid & 15) * 4;
    float s[4];
#pragma unroll
    for (int j = 0; j < 4; j++)
      s[j] = osp[(0 * 16 + row) * 64 + c4 + j] + osp[(1 * 16 + row) * 64 + c4 + j] +
             osp[(2 * 16 + row) * 64 + c4 + j] + osp[(3 * 16 + row) * 64 + c4 + j];
    ushort4 pk = make_ushort4(f2bf(s[0]), f2bf(s[1]), f2bf(s[2]), f2bf(s[3]));
    *(ushort4*)(out + (size_t)(r0 + row) * 64 + c4) = pk;
  }
}

// --------------------------- flash attention --------------------------------
// grid (128,4), block 512 (8 waves, kv-split 8). Transposed math:
//   S^T[kv][q] = K Q^T  (A=K-frag, B=Q-frag, both natural row-major)
//   O^T[d][q]  = V^T P^T (A=vhT-frag, B=P-frag from packed LDS)
// Mask scale is per-column q = c16 -> one scalar/lane. No kv-loop barriers.
__global__ __launch_bounds__(512, 4) void attn_kernel(
    const u16* __restrict__ qh, const u16* __restrict__ kh,
    const u16* __restrict__ vhT, const float* __restrict__ m,
    float* __restrict__ y) {
  __shared__ float Os[8][64][17];    // [w][d][q] +1 pad        34.8 KB
  __shared__ float Ls[8][16];
  __shared__ u16  Pl[8][16][68];     // [w][q][kv] +4 pad       17.4 KB
  const int tid = threadIdx.x;
  const int lane = tid & 63, w = tid >> 6;
  const int c16 = lane & 15, quad = lane >> 4;
  const int b = blockIdx.y;
  const int q0 = blockIdx.x * 16;

  // Q B-frags (n=q=c16, k=d contiguous), persistent
  bf16x8 qf[2];
  {
    const u16* qp = qh + (size_t)(b * 2048 + q0 + c16) * 64 + quad * 8;
    qf[0] = *(const bf16x8*)qp;
    qf[1] = *(const bf16x8*)(qp + 32);
  }
  const float fscale = 0.125f * m[b * 2048 + q0 + c16];

  f32x4 oacc[4];
#pragma unroll
  for (int nt = 0; nt < 4; nt++)
#pragma unroll
    for (int j = 0; j < 4; j++) oacc[nt][j] = 0.0f;
  float lsum = 0.0f;

  const u16* kb = kh + (size_t)b * 131072;
  const u16* vb = vhT + (size_t)b * 131072;

  for (int c = 0; c < 4; c++) {
    const int kv0 = w * 64 + c * 512;
    // ---- S^T = K Q^T ----
    f32x4 sacc[4];
#pragma unroll
    for (int nt = 0; nt < 4; nt++)
#pragma unroll
      for (int j = 0; j < 4; j++) sacc[nt][j] = 0.0f;
#pragma unroll
    for (int ks = 0; ks < 2; ks++)
#pragma unroll
      for (int nt = 0; nt < 4; nt++) {
        bf16x8 kf = *(const bf16x8*)(kb + (size_t)(kv0 + nt * 16 + c16) * 64 + ks * 32 + quad * 8);
        sacc[nt] = __builtin_amdgcn_mfma_f32_16x16x32_bf16(kf, qf[ks], sacc[nt], 0, 0, 0);
      }
    // ---- prefetch V A-frags for ks2=0 (fly during softmax) ----
    bf16x8 vf0[4];
#pragma unroll
    for (int nt = 0; nt < 4; nt++)
      vf0[nt] = *(const bf16x8*)(vb + (size_t)(nt * 16 + c16) * 2048 + kv0 + quad * 8);
    // ---- p = exp(m*s/8); per-lane l partial (no max: |s*m/8| small) ----
#pragma unroll
    for (int nt = 0; nt < 4; nt++)
#pragma unroll
      for (int rr = 0; rr < 4; rr++) {
        float p = __expf(sacc[nt][rr] * fscale);
        sacc[nt][rr] = p;
        lsum += p;
      }
    // ---- pack P^T rows: lane holds P[q=c16][kv=nt*16+quad*4+rr] ----
#pragma unroll
    for (int nt = 0; nt < 4; nt++) {
      ushort4 pk = make_ushort4(f2bf(sacc[nt][0]), f2bf(sacc[nt][1]),
                                f2bf(sacc[nt][2]), f2bf(sacc[nt][3]));
      *(ushort4*)&Pl[w][c16][nt * 16 + quad * 4] = pk;
    }
    // ---- O^T += V^T P^T (wave-private LDS, DS in-order; no barrier) ----
    bf16x8 vf1[4];
#pragma unroll
    for (int nt = 0; nt < 4; nt++)
      vf1[nt] = *(const bf16x8*)(vb + (size_t)(nt * 16 + c16) * 2048 + kv0 + 32 + quad * 8);
    {
      bf16x8 pf = *(const bf16x8*)&Pl[w][c16][quad * 8];
#pragma unroll
      for (int nt = 0; nt < 4; nt++)
        oacc[nt] = __builtin_amdgcn_mfma_f32_16x16x32_bf16(vf0[nt], pf, oacc[nt], 0, 0, 0);
    }
    {
      bf16x8 pf = *(const bf16x8*)&Pl[w][c16][32 + quad * 8];
#pragma unroll
      for (int nt = 0; nt < 4; nt++)
        oacc[nt] = __builtin_amdgcn_mfma_f32_16x16x32_bf16(vf1[nt], pf, oacc[nt], 0, 0, 0);
    }
  }

  // ---- l: sum the 4 lanes sharing c16 (quads) ----
  lsum += __shfl_xor(lsum, 16);
  lsum += __shfl_xor(lsum, 32);

  // ---- publish partials, combine across kv-split ----
#pragma unroll
  for (int nt = 0; nt < 4; nt++)
#pragma unroll
    for (int rr = 0; rr < 4; rr++)
      Os[w][nt * 16 + quad * 4 + rr][c16] = oacc[nt][rr];
  if (quad == 0) Ls[w][c16] = lsum;
  __syncthreads();

#pragma unroll
  for (int e = tid; e < 1024; e += 512) {
    const int qq = e >> 6, d = e & 63;
    float s = 0.0f, l = 0.0f;
#pragma unroll
    for (int ww = 0; ww < 8; ww++) { s += Os[ww][d][qq]; l += Ls[ww][qq]; }
    y[(size_t)(b * 2048 + q0 + qq) * 64 + d] = s / l;
  }
}

// ---------------------------------------------------------------------------
extern "C" void kernel_launch(void* const* d_in, const int* in_sizes, int n_in,
                              void* d_out, int out_size, void* d_ws, size_t ws_size,
                              hipStream_t stream) {
  (void)in_sizes; (void)n_in; (void)out_size; (void)ws_size;
  const float* q  = (const float*)d_in[0];
  const float* k  = (const float*)d_in[1];
  const float* v  = (const float*)d_in[2];
  const float* m  = (const float*)d_in[3];
  const float* Wq = (const float*)d_in[4];
  const float* Wk = (const float*)d_in[5];
  const float* Wv = (const float*)d_in[6];
  float* y = (float*)d_out;

  u16* qh  = (u16*)d_ws;          // [4][2048][64] bf16  (1 MB)
  u16* kh  = qh + 524288;         // [4][2048][64] bf16  (1 MB)
  u16* vhT = kh + 524288;         // [4][64][2048] bf16  (1 MB)
  u16* Wbf = vhT + 524288;        // [3][64][1024] bf16  (384 KB)

  wcvt_kernel<<<dim3(192), 256, 0, stream>>>(Wq, Wk, Wv, Wbf);
  proj_kernel<<<dim3(1536), 256, 0, stream>>>(q, k, v, Wbf, qh, kh, vhT);
  attn_kernel<<<dim3(128, 4), 512, 0, stream>>>(qh, kh, vhT, m, y);
}

// Round 3
// 167.120 us; speedup vs baseline: 1.0630x; 1.0630x over previous
//
#include <hip/hip_runtime.h>
#include <stdint.h>

// ---------------------------------------------------------------------------
// MaskedAttentionHead: B=4, S=2048, d_model=1024, d_k=64
// R11 == R10 resubmit (R2 bench was a container-level infra failure; static
// re-audit found no divergent barrier, no unsatisfiable vmcnt, no OOB).
// R10: R9 post-mortem — occupancy theory falsified (occ 17->33% yet 40->43us;
// VGPR 88->52 shows the compiler serialized the X burst). Common bottleneck of
// R8/R9: 1536 one-shot blocks, serial per-block chain, ~2.4 TB/s consumed.
// Fix: persistent pipelined blocks. grid=256 (1/CU), 6 tiles/block, fp32 X
// staged direct-to-LDS via global_load_lds (0 VGPR), double-buffered with
// counted vmcnt(16) + raw s_barrier (loads stay in flight across barriers),
// W frags persistent in 128 VGPRs (loaded once from L2; no W LDS/barriers).
// ds_read bank spread via pre-swizzled global source (rule #21), 2-way=free.
// vmcnt ledger/wave: stage_t[16], store[1], stage_{t+1}[16] -> vmcnt(16).
// attn/wcvt unchanged (attn still unprofiled; should appear in top-5 next).
// ---------------------------------------------------------------------------

typedef __bf16 bf16x8 __attribute__((ext_vector_type(8)));
typedef float  f32x4  __attribute__((ext_vector_type(4)));
typedef unsigned short u16;
typedef unsigned int   u32;

__device__ __forceinline__ u16 f2bf(float f) {
  u32 u = __float_as_uint(f);
  u += 0x7fffu + ((u >> 16) & 1u);          // round-to-nearest-even
  return (u16)(u >> 16);
}

// --------------------------- W fp32 -> bf16 --------------------------------
__global__ __launch_bounds__(256) void wcvt_kernel(
    const float* __restrict__ Wq, const float* __restrict__ Wk,
    const float* __restrict__ Wv, u16* __restrict__ Wbf) {
  int i = (blockIdx.x * 256 + threadIdx.x) * 4;   // 3*64*1024 = 196608 total
  const float* src = (i < 65536) ? Wq : (i < 131072) ? Wk : Wv;
  int off = i & 65535;
  float4 f = *(const float4*)(src + off);
  *(ushort4*)(Wbf + i) = make_ushort4(f2bf(f.x), f2bf(f.y), f2bf(f.z), f2bf(f.w));
}

// --------------------------- projections -----------------------------------
// grid 256 (1 block/CU), block 256 (4 waves). Tile ids gt = b*6 + t in
// [0,1536): which = gt>>9, r0 = (gt&511)*16. Per tile: 64 KB fp32 X staged
// to LDS dbuf by global_load_lds (wave w stages rows 4w..4w+3, 16x 1KB,
// source lane-XOR-preswizzled so compute ds_reads are bank-spread); K-split
// across waves (wave w owns cols w*64+qq*256); W B-frags live in VGPRs for
// the whole block. 2 raw barriers/tile, vmcnt never drained mid-loop.
__global__ __launch_bounds__(256, 1) void proj_kernel(
    const float* __restrict__ q, const float* __restrict__ k,
    const float* __restrict__ v, const u16* __restrict__ Wbf,
    u16* __restrict__ qh, u16* __restrict__ kh, u16* __restrict__ vhT) {
  __shared__ float xb[2][16][1024];   // 128 KB fp32 X tile, double-buffered
  __shared__ float os[4][16][68];     // 17.4 KB k-partials (+4 pad)
  const int tid = threadIdx.x;
  const int lane = tid & 63, w = tid >> 6;
  const int c16 = lane & 15, quad = lane >> 4;
  const int shq = c16 & 7;
  const int t0 = blockIdx.x * 6;

  bf16x8 wf[4][2][4];                 // [qq][ks][nt] = 128 VGPRs, persistent

#define LOADW(wh_)                                                            \
  {                                                                           \
    const u16* ws_ = Wbf + (wh_)*65536 + (size_t)c16 * 1024 + w * 64 + quad * 8; \
    _Pragma("unroll") for (int qq = 0; qq < 4; qq++)                          \
    _Pragma("unroll") for (int ks = 0; ks < 2; ks++)                          \
    _Pragma("unroll") for (int nt = 0; nt < 4; nt++)                          \
      wf[qq][ks][nt] = *(const bf16x8*)(ws_ + (size_t)nt * 16384 + qq * 256 + ks * 32); \
  }

  // LDS dest linear (gload_lds requirement); global source pre-XOR'd by row
  // so LDS[r][u] holds X[r][u^(r&7)] in 16-B units (rule #21 pairing).
#define STAGE(dst_, Xp_, r0_)                                                 \
  {                                                                           \
    _Pragma("unroll") for (int i = 0; i < 16; i++) {                          \
      const int rr_ = 4 * w + (i >> 2);                                       \
      const int qt_ = i & 3;                                                  \
      const float* gp_ = (Xp_) + (size_t)((r0_) + rr_) * 1024 + qt_ * 256 +   \
                         ((lane ^ (rr_ & 7)) << 2);                           \
      __builtin_amdgcn_global_load_lds(                                       \
          (const __attribute__((address_space(1))) u32*)gp_,                  \
          (__attribute__((address_space(3))) u32*)&xb[dst_][rr_][qt_ * 256],  \
          16, 0, 0);                                                          \
    }                                                                         \
  }

  // ---- prologue: W frags + tile 0, full drain once ----
  int wcur = t0 >> 9;
  LOADW(wcur);
  {
    const float* X0 = (wcur == 0) ? q : (wcur == 1) ? k : v;
    STAGE(0, X0, (t0 & 511) << 4);
  }
  asm volatile("s_waitcnt vmcnt(0)" ::: "memory");
  __builtin_amdgcn_s_barrier();
  __builtin_amdgcn_sched_barrier(0);

  int cur = 0;
#pragma unroll 1
  for (int t = 0; t < 6; t++) {
    const int gt = t0 + t;
    const int wh = gt >> 9;
    const int r0 = (gt & 511) << 4;

    // ---- issue next tile's stage; wait current tile (16 newer in flight) ----
    if (t < 5) {
      const int gt1 = gt + 1;
      const int wh1 = gt1 >> 9;
      const float* Xn = (wh1 == 0) ? q : (wh1 == 1) ? k : v;
      STAGE(cur ^ 1, Xn, (gt1 & 511) << 4);
      asm volatile("s_waitcnt vmcnt(16)" ::: "memory");
    } else {
      asm volatile("s_waitcnt vmcnt(0)" ::: "memory");
    }
    __builtin_amdgcn_s_barrier();            // buf[cur] ready; os free
    __builtin_amdgcn_sched_barrier(0);

    if (wh != wcur) { LOADW(wh); wcur = wh; }   // 2-3 boundary blocks only

    // ---- compute tile from LDS: ds_read fp32 (swizzled) -> cvt -> MFMA ----
    f32x4 acc[4];
#pragma unroll
    for (int nt = 0; nt < 4; nt++)
#pragma unroll
      for (int j = 0; j < 4; j++) acc[nt][j] = 0.0f;

#pragma unroll
    for (int qq = 0; qq < 4; qq++)
#pragma unroll
      for (int ks = 0; ks < 2; ks++) {
        const int ub = qq * 64 + w * 16 + ks * 8;      // 16-B unit, mult of 8
        const int p0 = ub + ((quad * 2) ^ shq);
        const int p1 = ub + ((quad * 2 + 1) ^ shq);
        f32x4 x0 = *(const f32x4*)&xb[cur][c16][p0 << 2];
        f32x4 x1 = *(const f32x4*)&xb[cur][c16][p1 << 2];
        union { u16 h[8]; bf16x8 v8; } cv;
        cv.h[0] = f2bf(x0[0]); cv.h[1] = f2bf(x0[1]);
        cv.h[2] = f2bf(x0[2]); cv.h[3] = f2bf(x0[3]);
        cv.h[4] = f2bf(x1[0]); cv.h[5] = f2bf(x1[1]);
        cv.h[6] = f2bf(x1[2]); cv.h[7] = f2bf(x1[3]);
#pragma unroll
        for (int nt = 0; nt < 4; nt++)
          acc[nt] = __builtin_amdgcn_mfma_f32_16x16x32_bf16(cv.v8, wf[qq][ks][nt],
                                                            acc[nt], 0, 0, 0);
      }

    // ---- publish k-partials ----
    float* osp = &os[0][0][0];
#pragma unroll
    for (int nt = 0; nt < 4; nt++)
#pragma unroll
      for (int rr = 0; rr < 4; rr++)
        osp[(w * 16 + quad * 4 + rr) * 68 + nt * 16 + c16] = acc[nt][rr];

    asm volatile("s_waitcnt lgkmcnt(0)" ::: "memory");
    __builtin_amdgcn_s_barrier();            // os complete; buf[cur] reads done
    __builtin_amdgcn_sched_barrier(0);

    // ---- combine 4 partials, store (1 vmem store/wave — in vmcnt ledger) ----
    if (wh == 2) {
      const int col = tid >> 2, s4 = (tid & 3) * 4;
      float s[4];
#pragma unroll
      for (int rr = 0; rr < 4; rr++)
        s[rr] = osp[(0 * 16 + s4 + rr) * 68 + col] + osp[(1 * 16 + s4 + rr) * 68 + col] +
                osp[(2 * 16 + s4 + rr) * 68 + col] + osp[(3 * 16 + s4 + rr) * 68 + col];
      const int bb = r0 >> 11, s0 = (r0 & 2047) + s4;
      ushort4 pk = make_ushort4(f2bf(s[0]), f2bf(s[1]), f2bf(s[2]), f2bf(s[3]));
      *(ushort4*)(vhT + ((size_t)bb * 64 + col) * 2048 + s0) = pk;
    } else {
      u16* out = (wh == 0) ? qh : kh;
      const int row = tid >> 4, c4 = (tid & 15) * 4;
      float s[4];
#pragma unroll
      for (int j = 0; j < 4; j++)
        s[j] = osp[(0 * 16 + row) * 68 + c4 + j] + osp[(1 * 16 + row) * 68 + c4 + j] +
               osp[(2 * 16 + row) * 68 + c4 + j] + osp[(3 * 16 + row) * 68 + c4 + j];
      ushort4 pk = make_ushort4(f2bf(s[0]), f2bf(s[1]), f2bf(s[2]), f2bf(s[3]));
      *(ushort4*)(out + (size_t)(r0 + row) * 64 + c4) = pk;
    }
    cur ^= 1;
  }
#undef LOADW
#undef STAGE
}

// --------------------------- flash attention --------------------------------
// grid (128,4), block 512 (8 waves, kv-split 8). Transposed math:
//   S^T[kv][q] = K Q^T  (A=K-frag, B=Q-frag, both natural row-major)
//   O^T[d][q]  = V^T P^T (A=vhT-frag, B=P-frag from packed LDS)
// Mask scale is per-column q = c16 -> one scalar/lane. No kv-loop barriers.
__global__ __launch_bounds__(512, 4) void attn_kernel(
    const u16* __restrict__ qh, const u16* __restrict__ kh,
    const u16* __restrict__ vhT, const float* __restrict__ m,
    float* __restrict__ y) {
  __shared__ float Os[8][64][17];    // [w][d][q] +1 pad        34.8 KB
  __shared__ float Ls[8][16];
  __shared__ u16  Pl[8][16][68];     // [w][q][kv] +4 pad       17.4 KB
  const int tid = threadIdx.x;
  const int lane = tid & 63, w = tid >> 6;
  const int c16 = lane & 15, quad = lane >> 4;
  const int b = blockIdx.y;
  const int q0 = blockIdx.x * 16;

  // Q B-frags (n=q=c16, k=d contiguous), persistent
  bf16x8 qf[2];
  {
    const u16* qp = qh + (size_t)(b * 2048 + q0 + c16) * 64 + quad * 8;
    qf[0] = *(const bf16x8*)qp;
    qf[1] = *(const bf16x8*)(qp + 32);
  }
  const float fscale = 0.125f * m[b * 2048 + q0 + c16];

  f32x4 oacc[4];
#pragma unroll
  for (int nt = 0; nt < 4; nt++)
#pragma unroll
    for (int j = 0; j < 4; j++) oacc[nt][j] = 0.0f;
  float lsum = 0.0f;

  const u16* kb = kh + (size_t)b * 131072;
  const u16* vb = vhT + (size_t)b * 131072;

  for (int c = 0; c < 4; c++) {
    const int kv0 = w * 64 + c * 512;
    // ---- S^T = K Q^T ----
    f32x4 sacc[4];
#pragma unroll
    for (int nt = 0; nt < 4; nt++)
#pragma unroll
      for (int j = 0; j < 4; j++) sacc[nt][j] = 0.0f;
#pragma unroll
    for (int ks = 0; ks < 2; ks++)
#pragma unroll
      for (int nt = 0; nt < 4; nt++) {
        bf16x8 kf = *(const bf16x8*)(kb + (size_t)(kv0 + nt * 16 + c16) * 64 + ks * 32 + quad * 8);
        sacc[nt] = __builtin_amdgcn_mfma_f32_16x16x32_bf16(kf, qf[ks], sacc[nt], 0, 0, 0);
      }
    // ---- prefetch V A-frags for ks2=0 (fly during softmax) ----
    bf16x8 vf0[4];
#pragma unroll
    for (int nt = 0; nt < 4; nt++)
      vf0[nt] = *(const bf16x8*)(vb + (size_t)(nt * 16 + c16) * 2048 + kv0 + quad * 8);
    // ---- p = exp(m*s/8); per-lane l partial (no max: |s*m/8| small) ----
#pragma unroll
    for (int nt = 0; nt < 4; nt++)
#pragma unroll
      for (int rr = 0; rr < 4; rr++) {
        float p = __expf(sacc[nt][rr] * fscale);
        sacc[nt][rr] = p;
        lsum += p;
      }
    // ---- pack P^T rows: lane holds P[q=c16][kv=nt*16+quad*4+rr] ----
#pragma unroll
    for (int nt = 0; nt < 4; nt++) {
      ushort4 pk = make_ushort4(f2bf(sacc[nt][0]), f2bf(sacc[nt][1]),
                                f2bf(sacc[nt][2]), f2bf(sacc[nt][3]));
      *(ushort4*)&Pl[w][c16][nt * 16 + quad * 4] = pk;
    }
    // ---- O^T += V^T P^T (wave-private LDS, DS in-order; no barrier) ----
    bf16x8 vf1[4];
#pragma unroll
    for (int nt = 0; nt < 4; nt++)
      vf1[nt] = *(const bf16x8*)(vb + (size_t)(nt * 16 + c16) * 2048 + kv0 + 32 + quad * 8);
    {
      bf16x8 pf = *(const bf16x8*)&Pl[w][c16][quad * 8];
#pragma unroll
      for (int nt = 0; nt < 4; nt++)
        oacc[nt] = __builtin_amdgcn_mfma_f32_16x16x32_bf16(vf0[nt], pf, oacc[nt], 0, 0, 0);
    }
    {
      bf16x8 pf = *(const bf16x8*)&Pl[w][c16][32 + quad * 8];
#pragma unroll
      for (int nt = 0; nt < 4; nt++)
        oacc[nt] = __builtin_amdgcn_mfma_f32_16x16x32_bf16(vf1[nt], pf, oacc[nt], 0, 0, 0);
    }
  }

  // ---- l: sum the 4 lanes sharing c16 (quads) ----
  lsum += __shfl_xor(lsum, 16);
  lsum += __shfl_xor(lsum, 32);

  // ---- publish partials, combine across kv-split ----
#pragma unroll
  for (int nt = 0; nt < 4; nt++)
#pragma unroll
    for (int rr = 0; rr < 4; rr++)
      Os[w][nt * 16 + quad * 4 + rr][c16] = oacc[nt][rr];
  if (quad == 0) Ls[w][c16] = lsum;
  __syncthreads();

#pragma unroll
  for (int e = tid; e < 1024; e += 512) {
    const int qq = e >> 6, d = e & 63;
    float s = 0.0f, l = 0.0f;
#pragma unroll
    for (int ww = 0; ww < 8; ww++) { s += Os[ww][d][qq]; l += Ls[ww][qq]; }
    y[(size_t)(b * 2048 + q0 + qq) * 64 + d] = s / l;
  }
}

// ---------------------------------------------------------------------------
extern "C" void kernel_launch(void* const* d_in, const int* in_sizes, int n_in,
                              void* d_out, int out_size, void* d_ws, size_t ws_size,
                              hipStream_t stream) {
  (void)in_sizes; (void)n_in; (void)out_size; (void)ws_size;
  const float* q  = (const float*)d_in[0];
  const float* k  = (const float*)d_in[1];
  const float* v  = (const float*)d_in[2];
  const float* m  = (const float*)d_in[3];
  const float* Wq = (const float*)d_in[4];
  const float* Wk = (const float*)d_in[5];
  const float* Wv = (const float*)d_in[6];
  float* y = (float*)d_out;

  u16* qh  = (u16*)d_ws;          // [4][2048][64] bf16  (1 MB)
  u16* kh  = qh + 524288;         // [4][2048][64] bf16  (1 MB)
  u16* vhT = kh + 524288;         // [4][64][2048] bf16  (1 MB)
  u16* Wbf = vhT + 524288;        // [3][64][1024] bf16  (384 KB)

  wcvt_kernel<<<dim3(192), 256, 0, stream>>>(Wq, Wk, Wv, Wbf);
  proj_kernel<<<dim3(256), 256, 0, stream>>>(q, k, v, Wbf, qh, kh, vhT);
  attn_kernel<<<dim3(128, 4), 512, 0, stream>>>(qh, kh, vhT, m, y);
}